// Round 6
// baseline (17.471 us; speedup 1.0000x reference)
//
#include <hip/hip_runtime.h>
#include <math.h>

#define TPB 64

__device__ __forceinline__ float2 cmul(float2 a, float2 b) {
    return make_float2(a.x*b.x - a.y*b.y, a.x*b.y + a.y*b.x);
}
__device__ __forceinline__ float2 cadd(float2 a, float2 b) {
    return make_float2(a.x + b.x, a.y + b.y);
}
__device__ __forceinline__ float2 cfma2(float2 a, float2 b, float2 c) {
    c.x = fmaf(a.x, b.x, fmaf(-a.y, b.y, c.x));
    c.y = fmaf(a.x, b.y, fmaf( a.y, b.x, c.y));
    return c;
}

// U = Rz(p2) @ Ry(p1) @ Rz(p0)   (fast native trig)
__device__ __forceinline__ void build_su2(const float* __restrict__ p, float2 U[2][2]) {
    float sb = __sinf(0.5f * p[1]), cb = __cosf(0.5f * p[1]);
    float ap = 0.5f * (p[0] + p[2]);
    float am = 0.5f * (p[0] - p[2]);
    float sap = __sinf(ap), cap = __cosf(ap);
    float sam = __sinf(am), cam = __cosf(am);
    U[0][0] = make_float2( cb * cap, -cb * sap);
    U[0][1] = make_float2(-sb * cam, -sb * sam);
    U[1][0] = make_float2( sb * cam, -sb * sam);
    U[1][1] = make_float2( cb * cap,  cb * sap);
}

// Single fused kernel: one thread per batch element, 4-qubit light-cone circuit.
// wire w <-> bit (3-w) of the amp index (wire0 = bit3, ..., wire3 = bit0).
// Lanes 0..15 build E01 (one 4x4 element each); lane 16 builds M = F^dag Z F.
__global__ __launch_bounds__(TPB) void qcnn_fused(
    const float* __restrict__ x,
    const float* __restrict__ W,
    const float* __restrict__ bias,
    const float* __restrict__ params,
    float* __restrict__ out,
    int n)
{
    __shared__ float2 sE[16];   // E01, row-major r*4+c
    __shared__ float  sM[4];    // m00, m11, Re M01, Im M01

    const int t   = threadIdx.x;
    const int tid = blockIdx.x * TPB + t;
    const int row = (tid < n) ? tid : (n - 1);

    // ---------- per-thread qfeat + trig ----------
    const float* xr = x + row * 16;
    const float4 xv0 = *(const float4*)(xr + 0);
    const float4 xv1 = *(const float4*)(xr + 4);
    const float4 xv2 = *(const float4*)(xr + 8);
    const float4 xv3 = *(const float4*)(xr + 12);
    float qf[4];
    #pragma unroll
    for (int q = 0; q < 4; ++q) {
        const float* wr = W + q * 16;
        float acc = bias[q];
        acc = fmaf(xv0.x, wr[0],  acc); acc = fmaf(xv0.y, wr[1],  acc);
        acc = fmaf(xv0.z, wr[2],  acc); acc = fmaf(xv0.w, wr[3],  acc);
        acc = fmaf(xv1.x, wr[4],  acc); acc = fmaf(xv1.y, wr[5],  acc);
        acc = fmaf(xv1.z, wr[6],  acc); acc = fmaf(xv1.w, wr[7],  acc);
        acc = fmaf(xv2.x, wr[8],  acc); acc = fmaf(xv2.y, wr[9],  acc);
        acc = fmaf(xv2.z, wr[10], acc); acc = fmaf(xv2.w, wr[11], acc);
        acc = fmaf(xv3.x, wr[12], acc); acc = fmaf(xv3.y, wr[13], acc);
        acc = fmaf(xv3.z, wr[14], acc); acc = fmaf(xv3.w, wr[15], acc);
        qf[q] = acc;
    }
    float c[4], s[4];
    #pragma unroll
    for (int q = 0; q < 4; ++q) {
        s[q] = __sinf(0.5f * qf[q]);
        c[q] = __cosf(0.5f * qf[q]);
    }
    const float h01 = 0.5f * qf[0] * qf[1];
    const float h12 = 0.5f * qf[1] * qf[2];
    const float h23 = 0.5f * qf[2] * qf[3];
    const float zs01 = __sinf(h01), zc01 = __cosf(h01);
    const float zs12 = __sinf(h12), zc12 = __cosf(h12);
    const float zs23 = __sinf(h23), zc23 = __cosf(h23);
    // ZZ pair factor: equal bits -> (zc, -zs); differing -> (zc, +zs)
    const float2 f01e = make_float2(zc01, -zs01), f01d = make_float2(zc01, zs01);
    const float2 f12e = make_float2(zc12, -zs12), f12d = make_float2(zc12, zs12);
    const float2 f23e = make_float2(zc23, -zs23), f23d = make_float2(zc23, zs23);

    // ---------- block setup: E01 (lanes 0..15), M (lane 16) ----------
    if (t < 16) {
        const float* pp = params;        // block (0,1) = first 15 params
        float2 A1[2][2], B1[2][2], A2[2][2], B2[2][2];
        build_su2(pp + 0,  A1);
        build_su2(pp + 3,  B1);
        build_su2(pp + 9,  A2);
        build_su2(pp + 12, B2);
        const float thx = pp[6], thy = pp[7], thz = pp[8];
        const float ha = 0.5f * (thx - thy), hb = 0.5f * (thx + thy), hz = 0.5f * thz;
        const float Sa = __sinf(ha), Ca = __cosf(ha);   // {00,11} subspace
        const float Sb = __sinf(hb), Cb = __cosf(hb);   // {01,10} subspace
        const float sz = __sinf(hz), cz = __cosf(hz);
        const float2 pz  = make_float2(cz, -sz);
        const float2 pzc = make_float2(cz,  sz);
        const float2 K00 = make_float2(Ca * pz.x,  Ca * pz.y);
        const float2 K03 = cmul(make_float2(0.f, -Sa), pz);
        const float2 K11 = make_float2(Cb * pzc.x, Cb * pzc.y);
        const float2 K12 = cmul(make_float2(0.f, -Sb), pzc);

        const int r = t >> 2, cc = t & 3;
        // column cc of T0 = A1 kron B1
        float2 T0c[4];
        #pragma unroll
        for (int j = 0; j < 4; ++j)
            T0c[j] = cmul(A1[j >> 1][cc >> 1], B1[j & 1][cc & 1]);
        // column cc of M1 = (ZZ*YY*XX) * T0
        float2 M1c[4];
        M1c[0] = cadd(cmul(K00, T0c[0]), cmul(K03, T0c[3]));
        M1c[1] = cadd(cmul(K11, T0c[1]), cmul(K12, T0c[2]));
        M1c[2] = cadd(cmul(K12, T0c[1]), cmul(K11, T0c[2]));
        M1c[3] = cadd(cmul(K03, T0c[0]), cmul(K00, T0c[3]));
        // E[r][cc] = sum_k (A2 kron B2)[r][k] * M1[k][cc]
        float2 acc = make_float2(0.f, 0.f);
        #pragma unroll
        for (int k = 0; k < 4; ++k)
            acc = cfma2(cmul(A2[r >> 1][k >> 1], B2[r & 1][k & 1]), M1c[k], acc);
        sE[t] = acc;
    } else if (t == 16) {
        float2 F[2][2];
        build_su2(params + 165, F);      // final SU2 on wire 0
        const float n00 = F[0][0].x*F[0][0].x + F[0][0].y*F[0][0].y;
        const float n10 = F[1][0].x*F[1][0].x + F[1][0].y*F[1][0].y;
        const float n01 = F[0][1].x*F[0][1].x + F[0][1].y*F[0][1].y;
        const float n11 = F[1][1].x*F[1][1].x + F[1][1].y*F[1][1].y;
        sM[0] = n00 - n10;               // M00
        sM[1] = n01 - n11;               // M11
        // M01 = conj(F00)*F01 - conj(F10)*F11
        sM[2] = (F[0][0].x*F[0][1].x + F[0][0].y*F[0][1].y)
              - (F[1][0].x*F[1][1].x + F[1][0].y*F[1][1].y);
        sM[3] = (F[0][0].x*F[0][1].y - F[0][0].y*F[0][1].x)
              - (F[1][0].x*F[1][1].y - F[1][0].y*F[1][1].x);
    }
    __syncthreads();

    float2 E[16];
    #pragma unroll
    for (int e = 0; e < 16; ++e) E[e] = sE[e];
    const float m00 = sM[0], m11 = sM[1], mr = sM[2], mi = sM[3];

    // ---------- distinct-value LUTs ----------
    // pair phases indexed by (eq01<<1)|eq12  (eq = bits equal)
    float2 p0112[4];
    p0112[0] = cmul(f01d, f12d);
    p0112[1] = cmul(f01d, f12e);
    p0112[2] = cmul(f01e, f12d);
    p0112[3] = cmul(f01e, f12e);
    // init phase: 8 distinct values indexed by (eq01<<2)|(eq12<<1)|eq23
    float2 p8[8];
    #pragma unroll
    for (int k = 0; k < 4; ++k) {
        p8[2*k]     = cmul(p0112[k], f23d);
        p8[2*k + 1] = cmul(p0112[k], f23e);
    }
    // magnitude factor tables: m01v[(b0<<1)|b1], m23v[(b2<<1)|b3]
    const float m01v[4] = { c[0]*c[1], c[0]*s[1], s[0]*c[1], s[0]*s[1] };
    const float m23v[4] = { c[2]*c[3], c[2]*s[3], s[2]*c[3], s[2]*s[3] };

    // ---------- init: L1 product state * L1 ZZ phases ----------
    float ar[16], ai[16];
    #pragma unroll
    for (int i = 0; i < 16; ++i) {
        const int b0 = (i >> 3) & 1, b1 = (i >> 2) & 1, b2 = (i >> 1) & 1, b3 = i & 1;
        const int eq01 = (b0 == b1), eq12 = (b1 == b2), eq23 = (b2 == b3);
        const float mag = m01v[i >> 2] * m23v[i & 3];
        const float2 ph = p8[(eq01 << 2) | (eq12 << 1) | eq23];
        ar[i] = mag * ph.x;
        ai[i] = mag * ph.y;
    }

    // ---------- L2: RY(qf0) bit3, RY(qf1) bit2, RY(qf2) bit1 (RY3 dead) ----------
    #pragma unroll
    for (int p = 0; p < 16; ++p) if (!(p & 8)) {
        const int q = p | 8;
        float lr = ar[p], li = ai[p], hr = ar[q], hi = ai[q];
        ar[p] = fmaf(c[0], lr, -s[0] * hr);  ai[p] = fmaf(c[0], li, -s[0] * hi);
        ar[q] = fmaf(s[0], lr,  c[0] * hr);  ai[q] = fmaf(s[0], li,  c[0] * hi);
    }
    #pragma unroll
    for (int p = 0; p < 16; ++p) if (!(p & 4)) {
        const int q = p | 4;
        float lr = ar[p], li = ai[p], hr = ar[q], hi = ai[q];
        ar[p] = fmaf(c[1], lr, -s[1] * hr);  ai[p] = fmaf(c[1], li, -s[1] * hi);
        ar[q] = fmaf(s[1], lr,  c[1] * hr);  ai[q] = fmaf(s[1], li,  c[1] * hi);
    }
    #pragma unroll
    for (int p = 0; p < 16; ++p) if (!(p & 2)) {
        const int q = p | 2;
        float lr = ar[p], li = ai[p], hr = ar[q], hi = ai[q];
        ar[p] = fmaf(c[2], lr, -s[2] * hr);  ai[p] = fmaf(c[2], li, -s[2] * hi);
        ar[q] = fmaf(s[2], lr,  c[2] * hr);  ai[q] = fmaf(s[2], li,  c[2] * hi);
    }

    // ---------- L2 ZZ phases: (0,1) on bits(3,2); (1,2) on bits(2,1) ----------
    #pragma unroll
    for (int i = 0; i < 16; ++i) {
        const int b0 = (i >> 3) & 1, b1 = (i >> 2) & 1, b2 = (i >> 1) & 1;
        const float2 gp = p0112[((b0 == b1) << 1) | (b1 == b2)];
        const float nr = ar[i] * gp.x - ai[i] * gp.y;
        const float ni = ar[i] * gp.y + ai[i] * gp.x;
        ar[i] = nr; ai[i] = ni;
    }

    // ---------- E01: 4x4 complex on v = 2*bit3 + bit2; groups = (bit1,bit0) ----------
    #pragma unroll
    for (int gq = 0; gq < 4; ++gq) {
        float xrv[4], xiv[4];
        #pragma unroll
        for (int v = 0; v < 4; ++v) { xrv[v] = ar[(v << 2) | gq]; xiv[v] = ai[(v << 2) | gq]; }
        #pragma unroll
        for (int r = 0; r < 4; ++r) {
            float yr = 0.f, yi = 0.f;
            #pragma unroll
            for (int v = 0; v < 4; ++v) {
                const float2 m = E[r * 4 + v];
                yr = fmaf(m.x, xrv[v], fmaf(-m.y, xiv[v], yr));
                yi = fmaf(m.x, xiv[v], fmaf( m.y, xrv[v], yi));
            }
            ar[(r << 2) | gq] = yr;
            ai[(r << 2) | gq] = yi;
        }
    }

    // ---------- measurement: d = <psi| (F^dag Z F)_0 |psi> on bit3 ----------
    float d = 0.f;
    #pragma unroll
    for (int i = 0; i < 8; ++i) {
        const float lr = ar[i], li = ai[i], hr = ar[i + 8], hi = ai[i + 8];
        const float cross = mr * (lr * hr + li * hi) - mi * (lr * hi - li * hr);
        d += m00 * (lr * lr + li * li) + m11 * (hr * hr + hi * hi) + 2.f * cross;
    }
    float y = 0.5f * (d + 1.0f);
    y = fminf(fmaxf(y, 1e-6f), 1.0f - 1e-6f);
    if (tid < n) out[tid] = y;
}

extern "C" void kernel_launch(void* const* d_in, const int* in_sizes, int n_in,
                              void* d_out, int out_size, void* d_ws, size_t ws_size,
                              hipStream_t stream) {
    (void)in_sizes; (void)n_in; (void)d_ws; (void)ws_size;
    const float* x      = (const float*)d_in[0];
    const float* W      = (const float*)d_in[1];
    const float* bias   = (const float*)d_in[2];
    const float* params = (const float*)d_in[3];
    float* out = (float*)d_out;
    hipLaunchKernelGGL(qcnn_fused, dim3((out_size + TPB - 1) / TPB), dim3(TPB), 0, stream,
                       x, W, bias, params, out, out_size);
}

// Round 7
// 11.861 us; speedup vs baseline: 1.4729x; 1.4729x over previous
//
#include <hip/hip_runtime.h>
#include <math.h>

#define TPB 256

__device__ __forceinline__ float2 cmul(float2 a, float2 b) {
    return make_float2(a.x*b.x - a.y*b.y, a.x*b.y + a.y*b.x);
}
__device__ __forceinline__ float2 cadd(float2 a, float2 b) {
    return make_float2(a.x + b.x, a.y + b.y);
}
__device__ __forceinline__ float2 cfma2(float2 a, float2 b, float2 c) {
    c.x = fmaf(a.x, b.x, fmaf(-a.y, b.y, c.x));
    c.y = fmaf(a.x, b.y, fmaf( a.y, b.x, c.y));
    return c;
}

// U = Rz(p2) @ Ry(p1) @ Rz(p0)   (fast native trig)
__device__ __forceinline__ void build_su2(const float* __restrict__ p, float2 U[2][2]) {
    float sb = __sinf(0.5f * p[1]), cb = __cosf(0.5f * p[1]);
    float ap = 0.5f * (p[0] + p[2]);
    float am = 0.5f * (p[0] - p[2]);
    float sap = __sinf(ap), cap = __cosf(ap);
    float sam = __sinf(am), cam = __cosf(am);
    U[0][0] = make_float2( cb * cap, -cb * sap);
    U[0][1] = make_float2(-sb * cam, -sb * sam);
    U[1][0] = make_float2( sb * cam, -sb * sam);
    U[1][1] = make_float2( cb * cap,  cb * sap);
}

// Single fused kernel: one thread per batch element, 4-qubit light-cone circuit.
// wire w <-> bit (3-w) of the amp index (wire0 = bit3, ..., wire3 = bit0).
// Lanes 0..15 of wave 0 build E01 (one 4x4 element each); lane 16 builds M = F^dag Z F.
__global__ __launch_bounds__(TPB) void qcnn_fused(
    const float* __restrict__ x,
    const float* __restrict__ W,
    const float* __restrict__ bias,
    const float* __restrict__ params,
    float* __restrict__ out,
    int n)
{
    __shared__ float2 sE[16];   // E01, row-major r*4+c
    __shared__ float  sM[4];    // m00, m11, Re M01, Im M01

    const int t   = threadIdx.x;
    const int tid = blockIdx.x * TPB + t;
    const int row = (tid < n) ? tid : (n - 1);

    // ---------- per-thread qfeat + trig ----------
    const float* xr = x + row * 16;
    const float4 xv0 = *(const float4*)(xr + 0);
    const float4 xv1 = *(const float4*)(xr + 4);
    const float4 xv2 = *(const float4*)(xr + 8);
    const float4 xv3 = *(const float4*)(xr + 12);
    float qf[4];
    #pragma unroll
    for (int q = 0; q < 4; ++q) {
        const float* wr = W + q * 16;
        float acc = bias[q];
        acc = fmaf(xv0.x, wr[0],  acc); acc = fmaf(xv0.y, wr[1],  acc);
        acc = fmaf(xv0.z, wr[2],  acc); acc = fmaf(xv0.w, wr[3],  acc);
        acc = fmaf(xv1.x, wr[4],  acc); acc = fmaf(xv1.y, wr[5],  acc);
        acc = fmaf(xv1.z, wr[6],  acc); acc = fmaf(xv1.w, wr[7],  acc);
        acc = fmaf(xv2.x, wr[8],  acc); acc = fmaf(xv2.y, wr[9],  acc);
        acc = fmaf(xv2.z, wr[10], acc); acc = fmaf(xv2.w, wr[11], acc);
        acc = fmaf(xv3.x, wr[12], acc); acc = fmaf(xv3.y, wr[13], acc);
        acc = fmaf(xv3.z, wr[14], acc); acc = fmaf(xv3.w, wr[15], acc);
        qf[q] = acc;
    }
    float c[4], s[4];
    #pragma unroll
    for (int q = 0; q < 4; ++q) {
        s[q] = __sinf(0.5f * qf[q]);
        c[q] = __cosf(0.5f * qf[q]);
    }
    const float h01 = 0.5f * qf[0] * qf[1];
    const float h12 = 0.5f * qf[1] * qf[2];
    const float h23 = 0.5f * qf[2] * qf[3];
    const float zs01 = __sinf(h01), zc01 = __cosf(h01);
    const float zs12 = __sinf(h12), zc12 = __cosf(h12);
    const float zs23 = __sinf(h23), zc23 = __cosf(h23);
    // ZZ pair factor: equal bits -> (zc, -zs); differing -> (zc, +zs)
    const float2 f01e = make_float2(zc01, -zs01), f01d = make_float2(zc01, zs01);
    const float2 f12e = make_float2(zc12, -zs12), f12d = make_float2(zc12, zs12);
    const float2 f23e = make_float2(zc23, -zs23), f23d = make_float2(zc23, zs23);

    // ---------- block setup: E01 (lanes 0..15), M (lane 16) ----------
    if (t < 16) {
        const float* pp = params;        // block (0,1) = first 15 params
        float2 A1[2][2], B1[2][2], A2[2][2], B2[2][2];
        build_su2(pp + 0,  A1);
        build_su2(pp + 3,  B1);
        build_su2(pp + 9,  A2);
        build_su2(pp + 12, B2);
        const float thx = pp[6], thy = pp[7], thz = pp[8];
        const float ha = 0.5f * (thx - thy), hb = 0.5f * (thx + thy), hz = 0.5f * thz;
        const float Sa = __sinf(ha), Ca = __cosf(ha);   // {00,11} subspace
        const float Sb = __sinf(hb), Cb = __cosf(hb);   // {01,10} subspace
        const float sz = __sinf(hz), cz = __cosf(hz);
        const float2 pz  = make_float2(cz, -sz);
        const float2 pzc = make_float2(cz,  sz);
        const float2 K00 = make_float2(Ca * pz.x,  Ca * pz.y);
        const float2 K03 = cmul(make_float2(0.f, -Sa), pz);
        const float2 K11 = make_float2(Cb * pzc.x, Cb * pzc.y);
        const float2 K12 = cmul(make_float2(0.f, -Sb), pzc);

        const int r = t >> 2, cc = t & 3;
        // column cc of T0 = A1 kron B1
        float2 T0c[4];
        #pragma unroll
        for (int j = 0; j < 4; ++j)
            T0c[j] = cmul(A1[j >> 1][cc >> 1], B1[j & 1][cc & 1]);
        // column cc of M1 = (ZZ*YY*XX) * T0
        float2 M1c[4];
        M1c[0] = cadd(cmul(K00, T0c[0]), cmul(K03, T0c[3]));
        M1c[1] = cadd(cmul(K11, T0c[1]), cmul(K12, T0c[2]));
        M1c[2] = cadd(cmul(K12, T0c[1]), cmul(K11, T0c[2]));
        M1c[3] = cadd(cmul(K03, T0c[0]), cmul(K00, T0c[3]));
        // E[r][cc] = sum_k (A2 kron B2)[r][k] * M1[k][cc]
        float2 acc = make_float2(0.f, 0.f);
        #pragma unroll
        for (int k = 0; k < 4; ++k)
            acc = cfma2(cmul(A2[r >> 1][k >> 1], B2[r & 1][k & 1]), M1c[k], acc);
        sE[t] = acc;
    } else if (t == 16) {
        float2 F[2][2];
        build_su2(params + 165, F);      // final SU2 on wire 0
        const float n00 = F[0][0].x*F[0][0].x + F[0][0].y*F[0][0].y;
        const float n10 = F[1][0].x*F[1][0].x + F[1][0].y*F[1][0].y;
        const float n01 = F[0][1].x*F[0][1].x + F[0][1].y*F[0][1].y;
        const float n11 = F[1][1].x*F[1][1].x + F[1][1].y*F[1][1].y;
        sM[0] = n00 - n10;               // M00
        sM[1] = n01 - n11;               // M11
        // M01 = conj(F00)*F01 - conj(F10)*F11
        sM[2] = (F[0][0].x*F[0][1].x + F[0][0].y*F[0][1].y)
              - (F[1][0].x*F[1][1].x + F[1][0].y*F[1][1].y);
        sM[3] = (F[0][0].x*F[0][1].y - F[0][0].y*F[0][1].x)
              - (F[1][0].x*F[1][1].y - F[1][0].y*F[1][1].x);
    }
    __syncthreads();

    float2 E[16];
    #pragma unroll
    for (int e = 0; e < 16; ++e) E[e] = sE[e];
    const float m00 = sM[0], m11 = sM[1], mr = sM[2], mi = sM[3];

    // ---------- distinct-value LUTs ----------
    // pair phases indexed by (eq01<<1)|eq12  (eq = bits equal)
    float2 p0112[4];
    p0112[0] = cmul(f01d, f12d);
    p0112[1] = cmul(f01d, f12e);
    p0112[2] = cmul(f01e, f12d);
    p0112[3] = cmul(f01e, f12e);
    // init phase: 8 distinct values indexed by (eq01<<2)|(eq12<<1)|eq23
    float2 p8[8];
    #pragma unroll
    for (int k = 0; k < 4; ++k) {
        p8[2*k]     = cmul(p0112[k], f23d);
        p8[2*k + 1] = cmul(p0112[k], f23e);
    }
    // magnitude factor tables: m01v[(b0<<1)|b1], m23v[(b2<<1)|b3]
    const float m01v[4] = { c[0]*c[1], c[0]*s[1], s[0]*c[1], s[0]*s[1] };
    const float m23v[4] = { c[2]*c[3], c[2]*s[3], s[2]*c[3], s[2]*s[3] };

    // ---------- init: L1 product state * L1 ZZ phases ----------
    float ar[16], ai[16];
    #pragma unroll
    for (int i = 0; i < 16; ++i) {
        const int b0 = (i >> 3) & 1, b1 = (i >> 2) & 1, b2 = (i >> 1) & 1, b3 = i & 1;
        const int eq01 = (b0 == b1), eq12 = (b1 == b2), eq23 = (b2 == b3);
        const float mag = m01v[i >> 2] * m23v[i & 3];
        const float2 ph = p8[(eq01 << 2) | (eq12 << 1) | eq23];
        ar[i] = mag * ph.x;
        ai[i] = mag * ph.y;
    }

    // ---------- L2: RY(qf0) bit3, RY(qf1) bit2, RY(qf2) bit1 (RY3 dead) ----------
    #pragma unroll
    for (int p = 0; p < 16; ++p) if (!(p & 8)) {
        const int q = p | 8;
        float lr = ar[p], li = ai[p], hr = ar[q], hi = ai[q];
        ar[p] = fmaf(c[0], lr, -s[0] * hr);  ai[p] = fmaf(c[0], li, -s[0] * hi);
        ar[q] = fmaf(s[0], lr,  c[0] * hr);  ai[q] = fmaf(s[0], li,  c[0] * hi);
    }
    #pragma unroll
    for (int p = 0; p < 16; ++p) if (!(p & 4)) {
        const int q = p | 4;
        float lr = ar[p], li = ai[p], hr = ar[q], hi = ai[q];
        ar[p] = fmaf(c[1], lr, -s[1] * hr);  ai[p] = fmaf(c[1], li, -s[1] * hi);
        ar[q] = fmaf(s[1], lr,  c[1] * hr);  ai[q] = fmaf(s[1], li,  c[1] * hi);
    }
    #pragma unroll
    for (int p = 0; p < 16; ++p) if (!(p & 2)) {
        const int q = p | 2;
        float lr = ar[p], li = ai[p], hr = ar[q], hi = ai[q];
        ar[p] = fmaf(c[2], lr, -s[2] * hr);  ai[p] = fmaf(c[2], li, -s[2] * hi);
        ar[q] = fmaf(s[2], lr,  c[2] * hr);  ai[q] = fmaf(s[2], li,  c[2] * hi);
    }

    // ---------- L2 ZZ phases: (0,1) on bits(3,2); (1,2) on bits(2,1) ----------
    #pragma unroll
    for (int i = 0; i < 16; ++i) {
        const int b0 = (i >> 3) & 1, b1 = (i >> 2) & 1, b2 = (i >> 1) & 1;
        const float2 gp = p0112[((b0 == b1) << 1) | (b1 == b2)];
        const float nr = ar[i] * gp.x - ai[i] * gp.y;
        const float ni = ar[i] * gp.y + ai[i] * gp.x;
        ar[i] = nr; ai[i] = ni;
    }

    // ---------- E01: 4x4 complex on v = 2*bit3 + bit2; groups = (bit1,bit0) ----------
    #pragma unroll
    for (int gq = 0; gq < 4; ++gq) {
        float xrv[4], xiv[4];
        #pragma unroll
        for (int v = 0; v < 4; ++v) { xrv[v] = ar[(v << 2) | gq]; xiv[v] = ai[(v << 2) | gq]; }
        #pragma unroll
        for (int r = 0; r < 4; ++r) {
            float yr = 0.f, yi = 0.f;
            #pragma unroll
            for (int v = 0; v < 4; ++v) {
                const float2 m = E[r * 4 + v];
                yr = fmaf(m.x, xrv[v], fmaf(-m.y, xiv[v], yr));
                yi = fmaf(m.x, xiv[v], fmaf( m.y, xrv[v], yi));
            }
            ar[(r << 2) | gq] = yr;
            ai[(r << 2) | gq] = yi;
        }
    }

    // ---------- measurement: d = <psi| (F^dag Z F)_0 |psi> on bit3 ----------
    float d = 0.f;
    #pragma unroll
    for (int i = 0; i < 8; ++i) {
        const float lr = ar[i], li = ai[i], hr = ar[i + 8], hi = ai[i + 8];
        const float cross = mr * (lr * hr + li * hi) - mi * (lr * hi - li * hr);
        d += m00 * (lr * lr + li * li) + m11 * (hr * hr + hi * hi) + 2.f * cross;
    }
    float y = 0.5f * (d + 1.0f);
    y = fminf(fmaxf(y, 1e-6f), 1.0f - 1e-6f);
    if (tid < n) out[tid] = y;
}

extern "C" void kernel_launch(void* const* d_in, const int* in_sizes, int n_in,
                              void* d_out, int out_size, void* d_ws, size_t ws_size,
                              hipStream_t stream) {
    (void)in_sizes; (void)n_in; (void)d_ws; (void)ws_size;
    const float* x      = (const float*)d_in[0];
    const float* W      = (const float*)d_in[1];
    const float* bias   = (const float*)d_in[2];
    const float* params = (const float*)d_in[3];
    float* out = (float*)d_out;
    hipLaunchKernelGGL(qcnn_fused, dim3((out_size + TPB - 1) / TPB), dim3(TPB), 0, stream,
                       x, W, bias, params, out, out_size);
}